// Round 2
// baseline (217.926 us; speedup 1.0000x reference)
//
#include <hip/hip_runtime.h>
#include <math.h>

#define EPSF 1e-6f

struct F3   { float x, y, z; };
struct Quat { float x, y, z, w; };
struct Sim3 { F3 t; Quat q; float s; };

__device__ __forceinline__ float frcp(float x) { return __builtin_amdgcn_rcpf(x); }

__device__ __forceinline__ F3 cross3(F3 a, F3 b) {
    return { a.y*b.z - a.z*b.y, a.z*b.x - a.x*b.z, a.x*b.y - a.y*b.x };
}

__device__ __forceinline__ F3 quat_rotate(Quat q, F3 v) {
    F3 qv { q.x, q.y, q.z };
    F3 uv  = cross3(qv, v);
    F3 cuv = cross3(qv, uv);
    return { v.x + 2.0f*(q.w*uv.x + cuv.x),
             v.y + 2.0f*(q.w*uv.y + cuv.y),
             v.z + 2.0f*(q.w*uv.z + cuv.z) };
}

__device__ __forceinline__ Quat quat_mul(Quat a, Quat b) {
    return {
        a.w*b.x + a.x*b.w + a.y*b.z - a.z*b.y,
        a.w*b.y - a.x*b.z + a.y*b.w + a.z*b.x,
        a.w*b.z + a.x*b.y - a.y*b.x + a.z*b.w,
        a.w*b.w - a.x*b.x - a.y*b.y - a.z*b.z
    };
}

__device__ __forceinline__ Sim3 sim3_inv(Sim3 T) {
    Quat qi { -T.q.x, -T.q.y, -T.q.z, T.q.w };
    float si = frcp(T.s);   // s ~ exp(0.1N): well away from 0; 1-ulp rcp ok
    F3 r = quat_rotate(qi, T.t);
    return { { -si*r.x, -si*r.y, -si*r.z }, qi, si };
}

__device__ __forceinline__ Sim3 sim3_mul(Sim3 A, Sim3 B) {
    F3 r = quat_rotate(A.q, B.t);
    return { { A.t.x + A.s*r.x, A.t.y + A.s*r.y, A.t.z + A.s*r.z },
             quat_mul(A.q, B.q), A.s * B.s };
}

__device__ __forceinline__ Sim3 load_sim3(const float* __restrict__ p) {
    float4 a = *reinterpret_cast<const float4*>(p);
    float4 b = *reinterpret_cast<const float4*>(p + 4);
    return { {a.x, a.y, a.z}, {a.w, b.x, b.y, b.z}, b.w };
}

// atan2(y,x) for y >= 0, result in [0, pi]. Max abs err ~2e-7.
__device__ __forceinline__ float fast_atan2_pos(float y, float x) {
    float ax = fabsf(x);
    float mn = fminf(ax, y), mx = fmaxf(ax, y);
    float t  = mn * frcp(mx);
    float t2 = t * t;
    float p = fmaf(t2, -0.0117212f,  0.05265332f);
    p = fmaf(t2, p, -0.11643287f);
    p = fmaf(t2, p,  0.19354346f);
    p = fmaf(t2, p, -0.33262347f);
    p = fmaf(t2, p,  0.99997726f);
    float r = t * p;
    r = (y > ax)   ? 1.57079632679f - r : r;
    r = (x < 0.0f) ? 3.14159265359f - r : r;
    return r;
}

// Mirrors the jax reference's where() structure. sin/cos of theta come from
// the quaternion half-angle identity (theta = 2*atan2(nv,qw) exactly), which
// only feeds branches selected when !th_small (where th == theta).
__device__ __forceinline__ void sim3_log(Sim3 T, float out[7]) {
    float qx = T.q.x, qy = T.q.y, qz = T.q.z, qw = T.q.w;
    float nv2 = fmaf(qx, qx, fmaf(qy, qy, qz*qz));
    float nv  = sqrtf(nv2);
    float theta_r = 2.0f * fast_atan2_pos(nv, qw);
    float fac = (nv < EPSF) ? 2.0f : theta_r * frcp(nv);
    float px = fac*qx, py = fac*qy, pz = fac*qz;
    float sigma = __logf(T.s);
    float theta = sqrtf(fmaf(px, px, fmaf(py, py, pz*pz)));

    bool sig_small = fabsf(sigma) < EPSF;
    bool th_small  = theta < EPSF;
    float sg = sig_small ? 1.0f : sigma;
    float th = th_small  ? 1.0f : theta;
    float scale = __expf(sigma);
    float th2 = th*th, sg2 = sg*sg;
    float rsg  = frcp(sg);
    float rth2 = frcp(th2);
    float C = sig_small ? 1.0f : (scale - 1.0f) * rsg;

    // sin(theta), cos(theta) via identity (|q| ~ 1 but normalize anyway)
    float inv_q = frcp(nv2 + qw*qw);
    float sth = 2.0f * qw * nv * inv_q;
    float cth = (qw*qw - nv2) * inv_q;

    float A_ss = th_small ? 0.5f        : (1.0f - cth) * rth2;
    float B_ss = th_small ? (1.0f/6.0f) : (th - sth) * frcp(th2 * th);
    float a = scale * sth;
    float b = scale * cth;
    float c = th2 + sg2;
    float rc = frcp(c);
    float A_g = fmaf(a, sg, (1.0f - b)*th) * frcp(th * c);
    float B_g = (C - fmaf(b - 1.0f, sg, a*th) * rc) * rth2;
    float rsg2 = rsg * rsg;
    float A_ts = fmaf(sg - 1.0f, scale, 1.0f) * rsg2;
    float B_ts = fmaf(scale, fmaf(sg, sg - 2.0f, 2.0f), -2.0f) * (0.5f * rsg2 * rsg);
    float A = sig_small ? A_ss : (th_small ? A_ts : A_g);
    float B = sig_small ? B_ss : (th_small ? B_ts : B_g);

    // Phi = skew(phi); Q = Phi@Phi
    float P01 = -pz, P02 =  py;
    float P10 =  pz, P12 = -px;
    float P20 = -py, P21 =  px;
    float Q00 = P01*P10 + P02*P20;
    float Q01 = P02*P21;
    float Q02 = P01*P12;
    float Q10 = P12*P20;
    float Q11 = P10*P01 + P12*P21;
    float Q12 = P10*P02;
    float Q20 = P21*P10;
    float Q21 = P20*P01;
    float Q22 = P20*P02 + P21*P12;

    float W00 = fmaf(B, Q00, C);
    float W01 = fmaf(A, P01, B*Q01);
    float W02 = fmaf(A, P02, B*Q02);
    float W10 = fmaf(A, P10, B*Q10);
    float W11 = fmaf(B, Q11, C);
    float W12 = fmaf(A, P12, B*Q12);
    float W20 = fmaf(A, P20, B*Q20);
    float W21 = fmaf(A, P21, B*Q21);
    float W22 = fmaf(B, Q22, C);

    // tau = W^{-1} t via f32 adjugate/Cramer (FMA'd)
    float c00 = fmaf(W11, W22, -W12*W21);
    float c01 = fmaf(W12, W20, -W10*W22);
    float c02 = fmaf(W10, W21, -W11*W20);
    float det = fmaf(W00, c00, fmaf(W01, c01, W02*c02));
    float idet = frcp(det);
    float m01 = fmaf(W02, W21, -W01*W22);
    float m02 = fmaf(W01, W12, -W02*W11);
    float m11 = fmaf(W00, W22, -W02*W20);
    float m12 = fmaf(W02, W10, -W00*W12);
    float m21 = fmaf(W01, W20, -W00*W21);
    float m22 = fmaf(W00, W11, -W01*W10);
    float tx = T.t.x, ty = T.t.y, tz = T.t.z;
    out[0] = fmaf(c00, tx, fmaf(m01, ty, m02*tz)) * idet;
    out[1] = fmaf(c01, tx, fmaf(m11, ty, m12*tz)) * idet;
    out[2] = fmaf(c02, tx, fmaf(m21, ty, m22*tz)) * idet;
    out[3] = px; out[4] = py; out[5] = pz; out[6] = sigma;
}

__global__ void __launch_bounds__(256) pgo_kernel(
        const float* __restrict__ Twc,
        const float* __restrict__ Tp_inv,
        const float* __restrict__ To_inv,
        const float* __restrict__ pw,
        const float* __restrict__ ow,
        const int*   __restrict__ edges,
        const float* __restrict__ T_lc,
        float*       __restrict__ out,
        int n) {
    int i = blockIdx.x * blockDim.x + threadIdx.x;
    if (i >= n) return;
    size_t i8 = (size_t)i * 8;
    size_t i7 = (size_t)i * 7;

    // Issue ALL global loads up front (gathers first: longest latency).
    int2 e = *reinterpret_cast<const int2*>(edges + 2*(size_t)i);
    Sim3 Ta = load_sim3(Twc + (size_t)e.x * 8);
    Sim3 Tb = load_sim3(Twc + (size_t)e.y * 8);
    Sim3 Ti = load_sim3(Twc + i8);
    Sim3 Tj = load_sim3(Twc + i8 + 8);
    Sim3 Tp = load_sim3(Tp_inv + i8);
    Sim3 To = load_sim3(To_inv + i8);
    Sim3 Tl = load_sim3(T_lc + i8);

    Sim3 delta = sim3_mul(sim3_inv(Ti), Tj);

    float rp[7], ro[7], rl[7];
    sim3_log(sim3_mul(delta, Tp), rp);
    sim3_log(sim3_mul(delta, To), ro);
    sim3_log(sim3_mul(sim3_mul(sim3_inv(Ta), Tb), Tl), rl);

    #pragma unroll
    for (int k = 0; k < 7; ++k) {
        out[i7 + k] = fmaf(rp[k], pw[i7 + k], fmaf(ro[k], ow[i7 + k], rl[k]));
    }
}

extern "C" void kernel_launch(void* const* d_in, const int* in_sizes, int n_in,
                              void* d_out, int out_size, void* d_ws, size_t ws_size,
                              hipStream_t stream) {
    const float* Twc   = (const float*)d_in[0];
    const float* Tp    = (const float*)d_in[1];
    const float* To    = (const float*)d_in[2];
    const float* pw    = (const float*)d_in[3];
    const float* ow    = (const float*)d_in[4];
    const int*   edges = (const int*)d_in[5];
    const float* Tlc   = (const float*)d_in[6];
    float* out = (float*)d_out;

    int n = in_sizes[1] / 8;  // N_FRAME - 1
    const int block = 256;
    int grid = (n + block - 1) / block;
    pgo_kernel<<<grid, block, 0, stream>>>(Twc, Tp, To, pw, ow, edges, Tlc, out, n);
}

// Round 3
// 215.891 us; speedup vs baseline: 1.0094x; 1.0094x over previous
//
#include <hip/hip_runtime.h>
#include <math.h>

#define EPSF 1e-6f

struct F3   { float x, y, z; };
struct Quat { float x, y, z, w; };
struct Sim3 { F3 t; Quat q; float s; };

__device__ __forceinline__ float frcp(float x) { return __builtin_amdgcn_rcpf(x); }

__device__ __forceinline__ F3 cross3(F3 a, F3 b) {
    return { a.y*b.z - a.z*b.y, a.z*b.x - a.x*b.z, a.x*b.y - a.y*b.x };
}

__device__ __forceinline__ F3 quat_rotate(Quat q, F3 v) {
    F3 qv { q.x, q.y, q.z };
    F3 uv  = cross3(qv, v);
    F3 cuv = cross3(qv, uv);
    return { v.x + 2.0f*(q.w*uv.x + cuv.x),
             v.y + 2.0f*(q.w*uv.y + cuv.y),
             v.z + 2.0f*(q.w*uv.z + cuv.z) };
}

__device__ __forceinline__ Quat quat_mul(Quat a, Quat b) {
    return {
        a.w*b.x + a.x*b.w + a.y*b.z - a.z*b.y,
        a.w*b.y - a.x*b.z + a.y*b.w + a.z*b.x,
        a.w*b.z + a.x*b.y - a.y*b.x + a.z*b.w,
        a.w*b.w - a.x*b.x - a.y*b.y - a.z*b.z
    };
}

__device__ __forceinline__ Sim3 sim3_inv(Sim3 T) {
    Quat qi { -T.q.x, -T.q.y, -T.q.z, T.q.w };
    float si = frcp(T.s);
    F3 r = quat_rotate(qi, T.t);
    return { { -si*r.x, -si*r.y, -si*r.z }, qi, si };
}

__device__ __forceinline__ Sim3 sim3_mul(Sim3 A, Sim3 B) {
    F3 r = quat_rotate(A.q, B.t);
    return { { A.t.x + A.s*r.x, A.t.y + A.s*r.y, A.t.z + A.s*r.z },
             quat_mul(A.q, B.q), A.s * B.s };
}

__device__ __forceinline__ Sim3 load_sim3(const float* __restrict__ p) {
    float4 a = *reinterpret_cast<const float4*>(p);
    float4 b = *reinterpret_cast<const float4*>(p + 4);
    return { {a.x, a.y, a.z}, {a.w, b.x, b.y, b.z}, b.w };
}

// atan2(y,x) for y >= 0, result in [0, pi]. Max abs err ~2e-7.
__device__ __forceinline__ float fast_atan2_pos(float y, float x) {
    float ax = fabsf(x);
    float mn = fminf(ax, y), mx = fmaxf(ax, y);
    float t  = mn * frcp(mx);
    float t2 = t * t;
    float p = fmaf(t2, -0.0117212f,  0.05265332f);
    p = fmaf(t2, p, -0.11643287f);
    p = fmaf(t2, p,  0.19354346f);
    p = fmaf(t2, p, -0.33262347f);
    p = fmaf(t2, p,  0.99997726f);
    float r = t * p;
    r = (y > ax)   ? 1.57079632679f - r : r;
    r = (x < 0.0f) ? 3.14159265359f - r : r;
    return r;
}

__device__ __forceinline__ void sim3_log(Sim3 T, float out[7]) {
    float qx = T.q.x, qy = T.q.y, qz = T.q.z, qw = T.q.w;
    float nv2 = fmaf(qx, qx, fmaf(qy, qy, qz*qz));
    float nv  = sqrtf(nv2);
    float theta_r = 2.0f * fast_atan2_pos(nv, qw);
    float fac = (nv < EPSF) ? 2.0f : theta_r * frcp(nv);
    float px = fac*qx, py = fac*qy, pz = fac*qz;
    float sigma = __logf(T.s);
    float theta = sqrtf(fmaf(px, px, fmaf(py, py, pz*pz)));

    bool sig_small = fabsf(sigma) < EPSF;
    bool th_small  = theta < EPSF;
    float sg = sig_small ? 1.0f : sigma;
    float th = th_small  ? 1.0f : theta;
    float scale = __expf(sigma);
    float th2 = th*th, sg2 = sg*sg;
    float rsg  = frcp(sg);
    float rth2 = frcp(th2);
    float C = sig_small ? 1.0f : (scale - 1.0f) * rsg;

    // sin(theta), cos(theta) via quaternion half-angle identity
    float inv_q = frcp(nv2 + qw*qw);
    float sth = 2.0f * qw * nv * inv_q;
    float cth = (qw*qw - nv2) * inv_q;

    float A_ss = th_small ? 0.5f        : (1.0f - cth) * rth2;
    float B_ss = th_small ? (1.0f/6.0f) : (th - sth) * frcp(th2 * th);
    float a = scale * sth;
    float b = scale * cth;
    float c = th2 + sg2;
    float rc = frcp(c);
    float A_g = fmaf(a, sg, (1.0f - b)*th) * frcp(th * c);
    float B_g = (C - fmaf(b - 1.0f, sg, a*th) * rc) * rth2;
    float rsg2 = rsg * rsg;
    float A_ts = fmaf(sg - 1.0f, scale, 1.0f) * rsg2;
    float B_ts = fmaf(scale, fmaf(sg, sg - 2.0f, 2.0f), -2.0f) * (0.5f * rsg2 * rsg);
    float A = sig_small ? A_ss : (th_small ? A_ts : A_g);
    float B = sig_small ? B_ss : (th_small ? B_ts : B_g);

    float P01 = -pz, P02 =  py;
    float P10 =  pz, P12 = -px;
    float P20 = -py, P21 =  px;
    float Q00 = P01*P10 + P02*P20;
    float Q01 = P02*P21;
    float Q02 = P01*P12;
    float Q10 = P12*P20;
    float Q11 = P10*P01 + P12*P21;
    float Q12 = P10*P02;
    float Q20 = P21*P10;
    float Q21 = P20*P01;
    float Q22 = P20*P02 + P21*P12;

    float W00 = fmaf(B, Q00, C);
    float W01 = fmaf(A, P01, B*Q01);
    float W02 = fmaf(A, P02, B*Q02);
    float W10 = fmaf(A, P10, B*Q10);
    float W11 = fmaf(B, Q11, C);
    float W12 = fmaf(A, P12, B*Q12);
    float W20 = fmaf(A, P20, B*Q20);
    float W21 = fmaf(A, P21, B*Q21);
    float W22 = fmaf(B, Q22, C);

    float c00 = fmaf(W11, W22, -W12*W21);
    float c01 = fmaf(W12, W20, -W10*W22);
    float c02 = fmaf(W10, W21, -W11*W20);
    float det = fmaf(W00, c00, fmaf(W01, c01, W02*c02));
    float idet = frcp(det);
    float m01 = fmaf(W02, W21, -W01*W22);
    float m02 = fmaf(W01, W12, -W02*W11);
    float m11 = fmaf(W00, W22, -W02*W20);
    float m12 = fmaf(W02, W10, -W00*W12);
    float m21 = fmaf(W01, W20, -W00*W21);
    float m22 = fmaf(W00, W11, -W01*W10);
    float tx = T.t.x, ty = T.t.y, tz = T.t.z;
    out[0] = fmaf(c00, tx, fmaf(m01, ty, m02*tz)) * idet;
    out[1] = fmaf(c01, tx, fmaf(m11, ty, m12*tz)) * idet;
    out[2] = fmaf(c02, tx, fmaf(m21, ty, m22*tz)) * idet;
    out[3] = px; out[4] = py; out[5] = pz; out[6] = sigma;
}

#define BLK 256
#define ROWF (BLK * 7)   // 1792 floats per block per 7-wide array

__global__ void __launch_bounds__(BLK) pgo_kernel(
        const float* __restrict__ Twc,
        const float* __restrict__ Tp_inv,
        const float* __restrict__ To_inv,
        const float* __restrict__ pw,
        const float* __restrict__ ow,
        const int*   __restrict__ edges,
        const float* __restrict__ T_lc,
        float*       __restrict__ out,
        int n) {
    __shared__ float s_pw[ROWF];
    __shared__ float s_ow[ROWF];   // reused as the output staging buffer

    int tid = threadIdx.x;
    int i0  = blockIdx.x * BLK;
    int i   = i0 + tid;
    int cnt = min(BLK, n - i0);        // rows this block handles
    int cntf = cnt * 7;

    // ---- cooperative, fully-coalesced float4 staging of pw/ow ----
    {
        const float* pwb = pw + (size_t)i0 * 7;   // i0*7 is float4-aligned (i0 % 4 == 0 ... i0*7*4B, i0=256k -> 1792k floats)
        const float* owb = ow + (size_t)i0 * 7;
        int nq = cntf >> 2;
        for (int k = tid; k < nq; k += BLK) {
            reinterpret_cast<float4*>(s_pw)[k] = reinterpret_cast<const float4*>(pwb)[k];
            reinterpret_cast<float4*>(s_ow)[k] = reinterpret_cast<const float4*>(owb)[k];
        }
        for (int k = (nq << 2) + tid; k < cntf; k += BLK) {
            s_pw[k] = pwb[k];
            s_ow[k] = owb[k];
        }
    }

    float res[7];
    bool active = (i < n);
    if (active) {
        size_t i8 = (size_t)i * 8;

        // gathers first: longest latency chain (edges -> Ta/Tb)
        int2 e = *reinterpret_cast<const int2*>(edges + 2*(size_t)i);
        Sim3 Ta = load_sim3(Twc + (size_t)e.x * 8);
        Sim3 Tb = load_sim3(Twc + (size_t)e.y * 8);
        Sim3 Ti = load_sim3(Twc + i8);
        Sim3 Tj = load_sim3(Twc + i8 + 8);
        Sim3 Tp = load_sim3(Tp_inv + i8);
        Sim3 To = load_sim3(To_inv + i8);
        Sim3 Tl = load_sim3(T_lc + i8);

        Sim3 delta = sim3_mul(sim3_inv(Ti), Tj);

        float rp[7], ro[7], rl[7];
        sim3_log(sim3_mul(delta, Tp), rp);
        sim3_log(sim3_mul(delta, To), ro);
        sim3_log(sim3_mul(sim3_mul(sim3_inv(Ta), Tb), Tl), rl);

        __syncthreads();   // staging visible (uniform: all threads in block reach when any does? cnt==BLK here except last block)
        // NOTE: guarded sync is safe only if all threads take same path; see below.
        #pragma unroll
        for (int k = 0; k < 7; ++k) {
            res[k] = fmaf(rp[k], s_pw[7*tid + k], fmaf(ro[k], s_ow[7*tid + k], rl[k]));
        }
    } else {
        __syncthreads();   // matching barrier for inactive threads (same barrier id)
        #pragma unroll
        for (int k = 0; k < 7; ++k) res[k] = 0.0f;
    }

    __syncthreads();       // everyone done reading s_ow; now reuse it for output
    #pragma unroll
    for (int k = 0; k < 7; ++k) {
        s_ow[7*tid + k] = res[k];
    }
    __syncthreads();

    // ---- cooperative, fully-coalesced float4 store of out ----
    {
        float* outb = out + (size_t)i0 * 7;
        int nq = cntf >> 2;
        for (int k = tid; k < nq; k += BLK) {
            reinterpret_cast<float4*>(outb)[k] = reinterpret_cast<const float4*>(s_ow)[k];
        }
        for (int k = (nq << 2) + tid; k < cntf; k += BLK) {
            outb[k] = s_ow[k];
        }
    }
}

extern "C" void kernel_launch(void* const* d_in, const int* in_sizes, int n_in,
                              void* d_out, int out_size, void* d_ws, size_t ws_size,
                              hipStream_t stream) {
    const float* Twc   = (const float*)d_in[0];
    const float* Tp    = (const float*)d_in[1];
    const float* To    = (const float*)d_in[2];
    const float* pw    = (const float*)d_in[3];
    const float* ow    = (const float*)d_in[4];
    const int*   edges = (const int*)d_in[5];
    const float* Tlc   = (const float*)d_in[6];
    float* out = (float*)d_out;

    int n = in_sizes[1] / 8;  // N_FRAME - 1
    int grid = (n + BLK - 1) / BLK;
    pgo_kernel<<<grid, BLK, 0, stream>>>(Twc, Tp, To, pw, ow, edges, Tlc, out, n);
}